// Round 1
// baseline (78.243 us; speedup 1.0000x reference)
//
#include <hip/hip_runtime.h>

constexpr int KWIN = 100;
constexpr int HK   = KWIN / 2;      // 50
constexpr float EPS = 1e-12f;
constexpr int TSUB = 64;            // time frames per thread

__global__ __launch_bounds__(256) void man_kernel(
    const float* __restrict__ x, float* __restrict__ out,
    const int B, const int T, const int D)
{
    const int Dh   = D >> 1;                       // float2 per frame = 64
    const int gid  = blockIdx.x * 256 + threadIdx.x;
    const int lane = gid & 63;                     // d-pair index
    const int wave = gid >> 6;
    const int b    = wave & (8 - 1);               // B == 8
    const int sub  = wave >> 3;
    const int t0   = sub * TSUB;
    if (b >= B || t0 >= T) return;

    const float2* __restrict__ xb =
        reinterpret_cast<const float2*>(x) + (size_t)b * T * Dh + lane;
    float2* __restrict__ ob =
        reinterpret_cast<float2*>(out) + (size_t)b * T * Dh + lane;

    const float invK   = 1.0f / (float)KWIN;
    const float invKm1 = 1.0f / (float)(KWIN - 1);
    const float fK     = (float)KWIN;

    float sx0 = 0.f, sx1 = 0.f, sq0 = 0.f, sq1 = 0.f;

    const bool interior = (t0 - HK >= 0) && (t0 + TSUB - 1 + HK <= T - 1);

    if (interior) {
        // ---- fast path: no reflection anywhere ----
        const float2* p = xb + (size_t)(t0 - HK) * Dh;
        #pragma unroll 4
        for (int j = 0; j < KWIN; ++j) {
            float2 v = p[0];
            sx0 += v.x; sq0 = fmaf(v.x, v.x, sq0);
            sx1 += v.y; sq1 = fmaf(v.y, v.y, sq1);
            p += Dh;
        }
        const float2* pc = xb + (size_t)t0 * Dh;
        float2*       po = ob + (size_t)t0 * Dh;
        const ptrdiff_t OIN  =  (ptrdiff_t)HK * Dh;
        const ptrdiff_t OOUT = -(ptrdiff_t)HK * Dh;
        #pragma unroll 4
        for (int t = 0; t < TSUB; ++t) {
            float2 c  = pc[0];
            float2 vi = pc[OIN];     // x[t+50]
            float2 vo = pc[OOUT];    // x[t-50]
            float m0 = sx0 * invK;
            float m1 = sx1 * invK;
            float v0 = fmaxf((sq0 - fK * m0 * m0) * invKm1, 0.f);
            float v1 = fmaxf((sq1 - fK * m1 * m1) * invKm1, 0.f);
            float d0 = sqrtf(v0) + EPS;
            float d1 = sqrtf(v1) + EPS;
            float2 o;
            o.x = (c.x - m0) / d0;
            o.y = (c.y - m1) / d1;
            po[0] = o;
            sx0 += vi.x - vo.x; sq0 += vi.x * vi.x - vo.x * vo.x;
            sx1 += vi.y - vo.y; sq1 += vi.y * vi.y - vo.y * vo.y;
            pc += Dh; po += Dh;
        }
    } else {
        // ---- boundary path: reflect indexing (pad left 50, right 49) ----
        auto ridx = [T](int i) -> int {
            if (i < 0) i = -i;
            else if (i >= T) i = 2 * T - 2 - i;
            return i;
        };
        for (int j = t0 - HK; j < t0 + HK; ++j) {
            float2 v = xb[(size_t)ridx(j) * Dh];
            sx0 += v.x; sq0 = fmaf(v.x, v.x, sq0);
            sx1 += v.y; sq1 = fmaf(v.y, v.y, sq1);
        }
        const int t1 = (t0 + TSUB < T) ? t0 + TSUB : T;
        for (int t = t0; t < t1; ++t) {
            float2 c  = xb[(size_t)t * Dh];
            float2 vi = xb[(size_t)ridx(t + HK) * Dh];
            float2 vo = xb[(size_t)ridx(t - HK) * Dh];
            float m0 = sx0 * invK;
            float m1 = sx1 * invK;
            float v0 = fmaxf((sq0 - fK * m0 * m0) * invKm1, 0.f);
            float v1 = fmaxf((sq1 - fK * m1 * m1) * invKm1, 0.f);
            float d0 = sqrtf(v0) + EPS;
            float d1 = sqrtf(v1) + EPS;
            float2 o;
            o.x = (c.x - m0) / d0;
            o.y = (c.y - m1) / d1;
            ob[(size_t)t * Dh] = o;
            sx0 += vi.x - vo.x; sq0 += vi.x * vi.x - vo.x * vo.x;
            sx1 += vi.y - vo.y; sq1 += vi.y * vi.y - vo.y * vo.y;
        }
    }
}

extern "C" void kernel_launch(void* const* d_in, const int* in_sizes, int n_in,
                              void* d_out, int out_size, void* d_ws, size_t ws_size,
                              hipStream_t stream) {
    (void)in_sizes; (void)n_in; (void)d_ws; (void)ws_size; (void)out_size;
    const float* x = (const float*)d_in[0];
    float* out = (float*)d_out;
    const int B = 8, T = 16384, D = 128;
    const int NS = T / TSUB;                 // 256 subchunks
    const int total_threads = B * NS * 64;   // 131072
    dim3 block(256);
    dim3 grid(total_threads / 256);          // 512 blocks
    man_kernel<<<grid, block, 0, stream>>>(x, out, B, T, D);
}

// Round 2
// 56.277 us; speedup vs baseline: 1.3903x; 1.3903x over previous
//
#include <hip/hip_runtime.h>

constexpr int KWIN = 100;
constexpr int HK   = KWIN / 2;      // 50
constexpr float EPS = 1e-12f;
constexpr int TSUB = 64;            // frames per wave
constexpr int PB   = 25;            // prime batch width (25 float2 in flight)
constexpr int MBATCH = 16;          // main batch width (48 float2 in flight)

__global__ __launch_bounds__(256) void man_kernel(
    const float* __restrict__ x, float* __restrict__ out)
{
    constexpr int T  = 16384;
    constexpr int Dh = 64;          // float2 per frame

    // Locality mapping: 512 blocks; physical block i -> logical bb such that
    // XCD x (= i % 8, default round-robin) owns all 64 blocks of batch b = x.
    // Within a block: 4 waves = 4 consecutive 64-frame chunks of the same b,
    // so the center/in/out streams of neighboring chunks share L1/L2 lines.
    const int i   = blockIdx.x;
    const int bb  = (i & 7) * 64 + (i >> 3);   // bijective on [0,512)
    const int b   = bb >> 6;                   // batch index 0..7
    const int blk = bb & 63;                   // 256-frame region within b
    const int w   = threadIdx.x >> 6;          // wave 0..3
    const int lane = threadIdx.x & 63;         // d-pair
    const int t0  = (blk * 4 + w) * TSUB;

    const float2* __restrict__ xb =
        reinterpret_cast<const float2*>(x) + (size_t)b * T * Dh + lane;
    float2* __restrict__ ob =
        reinterpret_cast<float2*>(out) + (size_t)b * T * Dh + lane;

    auto ridx = [](int t) -> int {             // reflect index, branchless
        t = (t < 0) ? -t : t;
        return (t >= T) ? (2 * T - 2 - t) : t;
    };

    const float invK   = 1.0f / (float)KWIN;
    const float invKm1 = 1.0f / (float)(KWIN - 1);
    const float fK     = (float)KWIN;

    float sx0 = 0.f, sx1 = 0.f, sq0 = 0.f, sq1 = 0.f;

    // ---- prime: window for frame t0 covers x[t0-50 .. t0+49] ----
    for (int jb = 0; jb < KWIN; jb += PB) {
        float2 v[PB];
        #pragma unroll
        for (int j = 0; j < PB; ++j)
            v[j] = xb[(size_t)ridx(t0 - HK + jb + j) * Dh];
        #pragma unroll
        for (int j = 0; j < PB; ++j) {
            sx0 += v[j].x; sq0 = fmaf(v[j].x, v[j].x, sq0);
            sx1 += v[j].y; sq1 = fmaf(v[j].y, v[j].y, sq1);
        }
    }

    // ---- main loop: batches of MBATCH frames, all loads issued up front ----
    for (int tb = 0; tb < TSUB; tb += MBATCH) {
        float2 c[MBATCH], vi[MBATCH], vo[MBATCH];
        #pragma unroll
        for (int j = 0; j < MBATCH; ++j) {
            const int t = t0 + tb + j;
            c[j]  = xb[(size_t)t * Dh];
            vi[j] = xb[(size_t)ridx(t + HK) * Dh];   // incoming x[t+50]
            vo[j] = xb[(size_t)ridx(t - HK) * Dh];   // outgoing x[t-50]
        }
        #pragma unroll
        for (int j = 0; j < MBATCH; ++j) {
            const float m0 = sx0 * invK;
            const float m1 = sx1 * invK;
            const float va0 = fmaxf((sq0 - fK * m0 * m0) * invKm1, 0.f);
            const float va1 = fmaxf((sq1 - fK * m1 * m1) * invKm1, 0.f);
            const float d0 = sqrtf(va0) + EPS;
            const float d1 = sqrtf(va1) + EPS;
            float2 o;
            o.x = (c[j].x - m0) / d0;
            o.y = (c[j].y - m1) / d1;
            ob[(size_t)(t0 + tb + j) * Dh] = o;
            sx0 += vi[j].x - vo[j].x;
            sq0 += vi[j].x * vi[j].x - vo[j].x * vo[j].x;
            sx1 += vi[j].y - vo[j].y;
            sq1 += vi[j].y * vi[j].y - vo[j].y * vo[j].y;
        }
    }
}

extern "C" void kernel_launch(void* const* d_in, const int* in_sizes, int n_in,
                              void* d_out, int out_size, void* d_ws, size_t ws_size,
                              hipStream_t stream) {
    (void)in_sizes; (void)n_in; (void)d_ws; (void)ws_size; (void)out_size;
    const float* x = (const float*)d_in[0];
    float* out = (float*)d_out;
    // 8 b * 256 chunks * 64 lanes = 131072 threads = 512 blocks * 256
    man_kernel<<<dim3(512), dim3(256), 0, stream>>>(x, out);
}

// Round 3
// 50.855 us; speedup vs baseline: 1.5386x; 1.1066x over previous
//
#include <hip/hip_runtime.h>

constexpr int KWIN = 100;
constexpr int HK   = 50;
constexpr float EPS = 1e-12f;
constexpr int TSUB = 256;     // frames per thread (chunk length)
constexpr int MB   = 16;      // main-loop batch (loads in flight)
constexpr int PB   = 20;      // prime batch (5 rounds)

__global__ __launch_bounds__(128) void man_kernel(
    const float* __restrict__ x, float* __restrict__ out)
{
    constexpr int T = 16384, D = 128;

    // Per-thread private ring: column `tid` of ring[slot][.].
    // Same-slot access across a wave = consecutive addresses -> conflict-free.
    // No cross-thread sharing -> no __syncthreads needed anywhere.
    __shared__ float ring[KWIN][128];   // 51200 B -> up to 3 blocks/CU

    const int tid = threadIdx.x;        // d index 0..127
    const int i   = blockIdx.x;         // 0..511
    // XCD x (= i%8) owns all 64 chunks of batch b = x, consecutive chunks
    // adjacent on the same XCD for halo L2 reuse.
    const int cg  = (i & 7) * 64 + (i >> 3);   // chunk-global 0..511
    const int b   = cg >> 6;
    const int t0  = (cg & 63) * TSUB;

    const float* __restrict__ xb = x   + (size_t)b * T * D + tid;
    float*       __restrict__ ob = out + (size_t)b * T * D + tid;

    auto ridx = [](int t) -> int {      // reflect index, branchless
        t = (t < 0) ? -t : t;
        return (t >= T) ? (2 * T - 2 - t) : t;
    };

    float sx = 0.f, sq = 0.f;

    // ---- prime: frames [t0-50, t0+49] -> ring slots 0..99 ----
    for (int jb = 0; jb < KWIN; jb += PB) {
        float g[PB];
        #pragma unroll
        for (int j = 0; j < PB; ++j)
            g[j] = xb[(size_t)ridx(t0 - HK + jb + j) * D];
        #pragma unroll
        for (int j = 0; j < PB; ++j) {
            sx += g[j];
            sq  = fmaf(g[j], g[j], sq);
            ring[jb + j][tid] = g[j];
        }
    }

    const float invK   = 1.0f / (float)KWIN;
    const float invKm1 = 1.0f / (float)(KWIN - 1);
    const float fK     = (float)KWIN;

    int ps = 0;    // slot holding frame (t - 50)
    int cs = HK;   // slot holding frame t

    for (int tb = 0; tb < TSUB; tb += MB) {
        float g[MB], c[MB], o[MB];
        // phase 1: issue next 16 incoming global loads (x[t+50])
        #pragma unroll
        for (int j = 0; j < MB; ++j)
            g[j] = xb[(size_t)ridx(t0 + tb + j + HK) * D];
        // phase 2: batch all ring reads (outgoing + center), one lgkm wait
        #pragma unroll
        for (int j = 0; j < MB; ++j) {
            int s = ps + j; if (s >= KWIN) s -= KWIN;
            o[j] = ring[s][tid];
            int s2 = cs + j; if (s2 >= KWIN) s2 -= KWIN;
            c[j] = ring[s2][tid];
        }
        // phase 3: compute outputs, slide window, refill ring
        #pragma unroll
        for (int j = 0; j < MB; ++j) {
            const float m  = sx * invK;
            const float va = fmaxf((sq - fK * m * m) * invKm1, 0.f);
            const float sd = sqrtf(va) + EPS;
            ob[(size_t)(t0 + tb + j) * D] = (c[j] - m) / sd;
            sx += g[j] - o[j];
            sq += g[j] * g[j] - o[j] * o[j];
            int s = ps + j; if (s >= KWIN) s -= KWIN;
            ring[s][tid] = g[j];      // overwrite the slot just vacated
        }
        ps += MB; if (ps >= KWIN) ps -= KWIN;
        cs += MB; if (cs >= KWIN) cs -= KWIN;
    }
}

extern "C" void kernel_launch(void* const* d_in, const int* in_sizes, int n_in,
                              void* d_out, int out_size, void* d_ws, size_t ws_size,
                              hipStream_t stream) {
    (void)in_sizes; (void)n_in; (void)d_ws; (void)ws_size; (void)out_size;
    const float* x = (const float*)d_in[0];
    float* out = (float*)d_out;
    // 8 b * 64 chunks * 128 d = 65536 threads = 512 blocks * 128
    man_kernel<<<dim3(512), dim3(128), 0, stream>>>(x, out);
}

// Round 4
// 35.607 us; speedup vs baseline: 2.1974x; 1.4282x over previous
//
#include <hip/hip_runtime.h>

constexpr int KWIN = 100;
constexpr int HK   = 50;
constexpr float EPS = 1e-12f;
constexpr int TSUB = 128;   // frames per thread
constexpr int MB   = 16;    // incoming loads batched per inner block
constexpr int PB   = 20;    // prime batch

__global__ __launch_bounds__(256, 2) void man_kernel(
    const float* __restrict__ x, float* __restrict__ out)
{
    constexpr int T = 16384, D = 128;

    const int i     = blockIdx.x;                // 0..511
    const int bb    = (i & 7) * 64 + (i >> 3);   // XCD x owns batch b = x
    const int b     = bb >> 6;                   // 0..7
    const int cpair = bb & 63;                   // pair of adjacent chunks
    const int w     = threadIdx.x >> 7;          // 0..1 (chunk within pair)
    const int tid   = threadIdx.x & 127;         // d column
    const int t0    = (cpair * 2 + w) * TSUB;

    const float* __restrict__ xb = x   + (size_t)b * T * D + tid;
    float*       __restrict__ ob = out + (size_t)b * T * D + tid;

    auto ridx = [](int t) -> int {               // reflect, branchless
        t = (t < 0) ? -t : t;
        return (t >= T) ? (2 * T - 2 - t) : t;
    };

    // 100-slot ring held ENTIRELY in registers: every index below is a
    // compile-time constant (loops fully unrolled), so no scratch spill.
    float v[KWIN];
    float sx = 0.f, sq = 0.f;

    // ---- prime: frames t0-50 .. t0+49 -> v[0..99] ----
    #pragma unroll
    for (int jb = 0; jb < KWIN; jb += PB) {
        float g[PB];
        #pragma unroll
        for (int j = 0; j < PB; ++j)
            g[j] = xb[(size_t)ridx(t0 - HK + jb + j) * D];
        #pragma unroll
        for (int j = 0; j < PB; ++j) {
            v[jb + j] = g[j];
            sx += g[j];
            sq  = fmaf(g[j], g[j], sq);
        }
    }

    const float invK   = 1.0f / (float)KWIN;
    const float invKm1 = 1.0f / (float)(KWIN - 1);
    const float fK     = (float)KWIN;

    // ---- main: 128 outputs, fully unrolled; ring slot jj%100 is static ----
    #pragma unroll
    for (int tb = 0; tb < TSUB; tb += MB) {
        float g[MB];
        #pragma unroll
        for (int j = 0; j < MB; ++j)
            g[j] = xb[(size_t)ridx(t0 + tb + j + HK) * D];  // incoming x[t+50]
        #pragma unroll
        for (int j = 0; j < MB; ++j) {
            const int jj = tb + j;
            const float c = v[(jj + HK) % KWIN];   // center x[t]
            const float o = v[jj % KWIN];          // outgoing x[t-50]
            const float m  = sx * invK;
            const float va = fmaxf((sq - fK * m * m) * invKm1, 0.f);
            const float sd = sqrtf(va) + EPS;
            ob[(size_t)(t0 + jj) * D] = (c - m) / sd;
            sx += g[j] - o;
            sq += g[j] * g[j] - o * o;
            v[jj % KWIN] = g[j];                   // refill freed slot
        }
    }
}

extern "C" void kernel_launch(void* const* d_in, const int* in_sizes, int n_in,
                              void* d_out, int out_size, void* d_ws, size_t ws_size,
                              hipStream_t stream) {
    (void)in_sizes; (void)n_in; (void)d_ws; (void)ws_size; (void)out_size;
    const float* x = (const float*)d_in[0];
    float* out = (float*)d_out;
    // 8 b * 128 chunks * 128 d = 131072 threads = 512 blocks * 256
    man_kernel<<<dim3(512), dim3(256), 0, stream>>>(x, out);
}